// Round 1
// baseline (860.317 us; speedup 1.0000x reference)
//
#include <hip/hip_runtime.h>
#include <hip/hip_bf16.h>
#include <math.h>

typedef __bf16 v8bf  __attribute__((ext_vector_type(8)));
typedef __bf16 v4bf  __attribute__((ext_vector_type(4)));
typedef float  v16f  __attribute__((ext_vector_type(16)));
typedef float  v4f   __attribute__((ext_vector_type(4)));
typedef float  f4v   __attribute__((ext_vector_type(4)));

#define N_ROWS    262144
#define OFF_COL   64
#define OFF_GRAM  1024
#define OFF_WT    66560
#define B1T_BYTE  1314816
#define B2T_BYTE  1445888
#define ZERO_BYTES 266240

// ---------------- prep: weight=w^2, sums, b1->bf16 transposed, b2->bf16 padded ----------------
extern "C" __global__ __launch_bounds__(256) void prep_k(
    const float* __restrict__ w, const float* __restrict__ b1,
    const float* __restrict__ b2, float* __restrict__ wsf) {
  float* weight = wsf + OFF_WT;
  __bf16* b1T = (__bf16*)((char*)wsf + B1T_BYTE);
  __bf16* b2T = (__bf16*)((char*)wsf + B2T_BYTE);
  int gid = blockIdx.x * 256 + threadIdx.x;
  float wi = w[gid];
  float wt = wi * wi;
  weight[gid] = wt;
  float s1 = wt, s2 = wt * wt, a1 = 0.f, a2 = 0.f;
  if (gid < 65536) {                 // b1T[h][p] = b1[p][h]
    int h = gid >> 8, p = gid & 255;
    float v = b1[p * 256 + h];
    b1T[gid] = (__bf16)v;
    a1 = fabsf(v);
  }
  if (gid < 4096) {                  // b2T[c][h] = b2[h][c], c padded 10->16 with 0
    int c = gid >> 8, h = gid & 255;
    float v = (c < 10) ? b2[h * 10 + c] : 0.f;
    b2T[gid] = (__bf16)v;
    a2 = fabsf(v);
  }
  #pragma unroll
  for (int off = 32; off > 0; off >>= 1) {
    s1 += __shfl_down(s1, off);
    s2 += __shfl_down(s2, off);
    a1 += __shfl_down(a1, off);
    a2 += __shfl_down(a2, off);
  }
  if ((threadIdx.x & 63) == 0) {
    atomicAdd(&wsf[1], s1);
    atomicAdd(&wsf[2], s2);
    if (blockIdx.x < 256) atomicAdd(&wsf[3], a1);
    if (blockIdx.x < 16)  atomicAdd(&wsf[4], a2);
  }
}

// ---------------- mlp: hdn=relu(x@b1), dropout, logits, CE, argmax ----------------
extern "C" __global__ __launch_bounds__(256, 2) void mlp_k(
    const float* __restrict__ x, const int* __restrict__ y,
    const float* __restrict__ du, float* __restrict__ wsf) {
  const __bf16* b1T = (const __bf16*)((const char*)wsf + B1T_BYTE);
  const __bf16* b2T = (const __bf16*)((const char*)wsf + B2T_BYTE);
  __shared__ union U {
    struct { __bf16 xs[128 * 40]; __bf16 b1s[256 * 40]; } m;   // main GEMM staging
    struct { __bf16 hk[128 * 136]; float lg[128 * 16]; } l;    // logits phase
  } sm;
  const int tid = threadIdx.x;
  const int wv = tid >> 6, L = tid & 63;
  const int l32 = L & 31, lh = L >> 5;
  const int mb = 64 * (wv >> 1), nb = 128 * (wv & 1);  // wave tile 64x128 of 128x256
  const long rowBase = (long)blockIdx.x * 128;

  v16f acc[2][4] = {};

  for (int kc = 0; kc < 256; kc += 32) {
    __syncthreads();
    // stage x chunk [128 rows x 32 k] fp32 -> bf16, row-major (A layout), stride 40
    #pragma unroll
    for (int i = 0; i < 4; i++) {
      int f = tid + 256 * i;
      int r = f >> 3, c4 = f & 7;
      f4v v = ((const f4v*)x)[(rowBase + r) * 64 + (kc >> 2) + c4];
      v4bf o;
      o[0] = (__bf16)v[0]; o[1] = (__bf16)v[1]; o[2] = (__bf16)v[2]; o[3] = (__bf16)v[3];
      *(v4bf*)&sm.m.xs[r * 40 + 4 * c4] = o;
    }
    // stage b1T chunk [256 n x 32 k] bf16 copy, stride 40
    #pragma unroll
    for (int i = 0; i < 4; i++) {
      int f = tid + 256 * i;
      int nr = f >> 2, c = f & 3;
      *(v8bf*)&sm.m.b1s[nr * 40 + 8 * c] = *(const v8bf*)&b1T[nr * 256 + kc + 8 * c];
    }
    __syncthreads();
    #pragma unroll
    for (int ks = 0; ks < 32; ks += 16) {
      v8bf a0 = *(const v8bf*)&sm.m.xs[(mb + l32) * 40 + ks + 8 * lh];
      v8bf a1 = *(const v8bf*)&sm.m.xs[(mb + 32 + l32) * 40 + ks + 8 * lh];
      v8bf b[4];
      #pragma unroll
      for (int tn = 0; tn < 4; tn++)
        b[tn] = *(const v8bf*)&sm.m.b1s[(nb + 32 * tn + l32) * 40 + ks + 8 * lh];
      #pragma unroll
      for (int tn = 0; tn < 4; tn++) {
        acc[0][tn] = __builtin_amdgcn_mfma_f32_32x32x16_bf16(a0, b[tn], acc[0][tn], 0, 0, 0);
        acc[1][tn] = __builtin_amdgcn_mfma_f32_32x32x16_bf16(a1, b[tn], acc[1][tn], 0, 0, 0);
      }
    }
  }
  // relu + inverted dropout, in-register (C layout: col=lane&31, row=(r&3)+8*(r>>2)+4*(lane>>5))
  #pragma unroll
  for (int tm = 0; tm < 2; tm++)
    #pragma unroll
    for (int tn = 0; tn < 4; tn++)
      #pragma unroll
      for (int r = 0; r < 16; r++) {
        int row = mb + 32 * tm + (r & 3) + 8 * (r >> 2) + 4 * lh;
        int cg = nb + 32 * tn + l32;
        float u = du[(rowBase + row) * 256 + cg];
        float v = acc[tm][tn][r];
        v = fmaxf(v, 0.f);
        acc[tm][tn][r] = (u > 0.3f) ? v * (1.0f / 0.7f) : 0.f;
      }

  // logits = hdnk @ b2 (padded to 16 cols) via 16x16x32 MFMA, h in two 128-chunks
  v4f lacc[2] = {};
  #pragma unroll
  for (int hc = 0; hc < 2; hc++) {
    __syncthreads();
    if ((wv & 1) == hc) {          // waves owning these h-cols spill to LDS
      #pragma unroll
      for (int tm = 0; tm < 2; tm++)
        #pragma unroll
        for (int tn = 0; tn < 4; tn++)
          #pragma unroll
          for (int r = 0; r < 16; r++) {
            int row = mb + 32 * tm + (r & 3) + 8 * (r >> 2) + 4 * lh;
            int cl = 32 * tn + l32;
            sm.l.hk[row * 136 + cl] = (__bf16)acc[tm][tn][r];
          }
    }
    __syncthreads();
    #pragma unroll
    for (int i = 0; i < 2; i++) {
      int mt = 2 * wv + i;         // 8 m-tiles of 16 rows across 4 waves
      #pragma unroll
      for (int kk = 0; kk < 4; kk++) {
        v8bf a  = *(const v8bf*)&sm.l.hk[(16 * mt + (L & 15)) * 136 + 32 * kk + 8 * (L >> 4)];
        v8bf bb = *(const v8bf*)&b2T[(L & 15) * 256 + 128 * hc + 32 * kk + 8 * (L >> 4)];
        lacc[i] = __builtin_amdgcn_mfma_f32_16x16x32_bf16(a, bb, lacc[i], 0, 0, 0);
      }
    }
  }
  // write logits (16x16 C layout: col=lane&15, row=4*(lane>>4)+r)
  #pragma unroll
  for (int i = 0; i < 2; i++) {
    int mt = 2 * wv + i;
    #pragma unroll
    for (int r = 0; r < 4; r++)
      sm.l.lg[(16 * mt + 4 * (L >> 4) + r) * 16 + (L & 15)] = lacc[i][r];
  }
  __syncthreads();
  float ce = 0.f;
  int cor = 0;
  if (tid < 128) {
    const float* lr = &sm.l.lg[tid * 16];
    float mx = lr[0];
    int am = 0;
    #pragma unroll
    for (int c = 1; c < 10; c++)
      if (lr[c] > mx) { mx = lr[c]; am = c; }   // strict > keeps first-max (jnp semantics)
    float s = 0.f;
    #pragma unroll
    for (int c = 0; c < 10; c++) s += expf(lr[c] - mx);
    int yt = y[rowBase + tid];
    ce = logf(s) + mx - lr[yt];
    cor = (am == yt) ? 1 : 0;
  }
  #pragma unroll
  for (int off = 32; off > 0; off >>= 1) ce += __shfl_down(ce, off);
  unsigned long long bal = __ballot(cor != 0);
  if (L == 0 && wv < 2) {
    atomicAdd(&wsf[0], ce);
    atomicAdd((int*)&wsf[8], (int)__popcll(bal));
  }
}

// ---------------- gram = x^T diag(w^2) x  (+ col = x^T w^2) ----------------
extern "C" __global__ __launch_bounds__(512, 1) void gram_k(
    const float* __restrict__ x, float* __restrict__ wsf) {
  const float* weight = wsf + OFF_WT;
  float* gram = wsf + OFF_GRAM;
  __shared__ __bf16 xT[256 * 40];
  __shared__ __bf16 wxT[256 * 40];
  const int tid = threadIdx.x;
  const int wv = tid >> 6, L = tid & 63;
  const int l32 = L & 31, lh = L >> 5;
  const int mb = 64 * (wv >> 1), nb = 128 * (wv & 1);  // 8 waves tile 256x256 as 4x2 of 64x128
  const long base = (long)blockIdx.x * 1024;
  v16f acc[2][4] = {};
  float colAcc = 0.f;
  for (int ch = 0; ch < 32; ch++) {
    long k0 = base + ch * 32;
    __syncthreads();
    // stage transposed: xT[col][k], wxT[col][k]; lanes stride-1 in k -> conflict-free LDS writes
    #pragma unroll
    for (int i = 0; i < 4; i++) {
      int f = tid + 512 * i;
      int k = f & 31, cg = f >> 5;      // cg in 0..63
      f4v v = ((const f4v*)x)[(k0 + k) * 64 + cg];
      float wk = weight[k0 + k];
      #pragma unroll
      for (int d = 0; d < 4; d++) {
        int col = 4 * cg + d;
        xT[col * 40 + k]  = (__bf16)v[d];
        wxT[col * 40 + k] = (__bf16)(wk * v[d]);
      }
    }
    __syncthreads();
    if (tid < 256) {                    // col partial from weighted chunk
      #pragma unroll
      for (int q = 0; q < 4; q++) {
        v8bf vv = *(const v8bf*)&wxT[tid * 40 + 8 * q];
        #pragma unroll
        for (int j = 0; j < 8; j++) colAcc += (float)vv[j];
      }
    }
    #pragma unroll
    for (int ks = 0; ks < 32; ks += 16) {
      v8bf a0 = *(const v8bf*)&xT[(mb + l32) * 40 + ks + 8 * lh];
      v8bf a1 = *(const v8bf*)&xT[(mb + 32 + l32) * 40 + ks + 8 * lh];
      v8bf b[4];
      #pragma unroll
      for (int tn = 0; tn < 4; tn++)
        b[tn] = *(const v8bf*)&wxT[(nb + 32 * tn + l32) * 40 + ks + 8 * lh];
      #pragma unroll
      for (int tn = 0; tn < 4; tn++) {
        acc[0][tn] = __builtin_amdgcn_mfma_f32_32x32x16_bf16(a0, b[tn], acc[0][tn], 0, 0, 0);
        acc[1][tn] = __builtin_amdgcn_mfma_f32_32x32x16_bf16(a1, b[tn], acc[1][tn], 0, 0, 0);
      }
    }
  }
  #pragma unroll
  for (int tm = 0; tm < 2; tm++)
    #pragma unroll
    for (int tn = 0; tn < 4; tn++)
      #pragma unroll
      for (int r = 0; r < 16; r++) {
        int row = mb + 32 * tm + (r & 3) + 8 * (r >> 2) + 4 * lh;
        int cg = nb + 32 * tn + l32;
        atomicAdd(&gram[row * 256 + cg], acc[tm][tn][r]);
      }
  if (tid < 256) atomicAdd(&wsf[OFF_COL + tid], colAcc);
}

// ---------------- finalize: bm, loss, acc ----------------
extern "C" __global__ __launch_bounds__(256) void fin_k(
    const float* __restrict__ wsf, float* __restrict__ out) {
  __shared__ float colS[256];
  __shared__ float red[256];
  int t = threadIdx.x;
  colS[t] = wsf[OFF_COL + t];
  __syncthreads();
  const float* gram = wsf + OFF_GRAM;
  float ct = colS[t];
  float bm = 0.f;
  for (int j = 0; j < 256; j++) {
    float d = gram[t * 256 + j] - ct * colS[j];
    if (j != t) bm += d * d;   // (1 - eye) masks diagonal
  }
  red[t] = bm;
  __syncthreads();
  for (int s = 128; s > 0; s >>= 1) {
    if (t < s) red[t] += red[t + s];
    __syncthreads();
  }
  if (t == 0) {
    float ce = wsf[0], wsum = wsf[1], w4 = wsf[2], ab1 = wsf[3], ab2 = wsf[4];
    int cor = *(const int*)&wsf[8];
    float loss = ce * wsum
               + 0.01f * (ab1 + ab2)
               + 0.001f * red[0]
               + 0.1f * w4
               + 100.f * (wsum - 1.f) * (wsum - 1.f);
    out[0] = loss;
    out[1] = (float)cor * (1.0f / 262144.0f);
  }
}

extern "C" void kernel_launch(void* const* d_in, const int* in_sizes, int n_in,
                              void* d_out, int out_size, void* d_ws, size_t ws_size,
                              hipStream_t stream) {
  const float* x  = (const float*)d_in[0];
  const int*   y  = (const int*)d_in[1];
  const float* du = (const float*)d_in[2];
  const float* b1 = (const float*)d_in[3];
  const float* b2 = (const float*)d_in[4];
  const float* w  = (const float*)d_in[5];
  float* wsf = (float*)d_ws;

  hipMemsetAsync(d_ws, 0, ZERO_BYTES, stream);                 // zero scalars+col+gram
  prep_k<<<1024, 256, 0, stream>>>(w, b1, b2, wsf);
  mlp_k<<<2048, 256, 0, stream>>>(x, y, du, wsf);
  gram_k<<<256, 512, 0, stream>>>(x, wsf);
  fin_k<<<1, 256, 0, stream>>>(wsf, (float*)d_out);
}

// Round 2
// 818.006 us; speedup vs baseline: 1.0517x; 1.0517x over previous
//
#include <hip/hip_runtime.h>
#include <hip/hip_bf16.h>
#include <math.h>

typedef __bf16 v8bf  __attribute__((ext_vector_type(8)));
typedef __bf16 v4bf  __attribute__((ext_vector_type(4)));
typedef float  v16f  __attribute__((ext_vector_type(16)));
typedef float  v4f   __attribute__((ext_vector_type(4)));
typedef float  f4v   __attribute__((ext_vector_type(4)));

// ws layout (floats unless noted):
//   [0..16)      scalars: 0=ce, 1=wsum, 2=w4, 3=ab1, 4=ab2, 8=cor(int)
//   [16..272)    col[256]
//   [1024..263168)  gram: 4 copies x 65536
//   [263168..525312) weight = w^2  (262144)
//   byte 2101248: b1T bf16 [256][256]
//   byte 2232320: b2T bf16 [16][256]
#define OFF_COL   16
#define OFF_GRAM  1024
#define OFF_WT    263168
#define B1T_BYTE  2101248
#define B2T_BYTE  2232320
#define ZERO_BYTES 1052672   // scalars+col+gram copies

// ---------------- prep: weight=w^2, sums, b1->bf16 transposed, b2->bf16 padded ----------------
extern "C" __global__ __launch_bounds__(256) void prep_k(
    const float* __restrict__ w, const float* __restrict__ b1,
    const float* __restrict__ b2, float* __restrict__ wsf) {
  float* weight = wsf + OFF_WT;
  __bf16* b1T = (__bf16*)((char*)wsf + B1T_BYTE);
  __bf16* b2T = (__bf16*)((char*)wsf + B2T_BYTE);
  int gid = blockIdx.x * 256 + threadIdx.x;
  float wi = w[gid];
  float wt = wi * wi;
  weight[gid] = wt;
  float s1 = wt, s2 = wt * wt, a1 = 0.f, a2 = 0.f;
  if (gid < 65536) {                 // b1T[h][p] = b1[p][h]
    int h = gid >> 8, p = gid & 255;
    float v = b1[p * 256 + h];
    b1T[gid] = (__bf16)v;
    a1 = fabsf(v);
  }
  if (gid < 4096) {                  // b2T[c][h] = b2[h][c], c padded 10->16 with 0
    int c = gid >> 8, h = gid & 255;
    float v = (c < 10) ? b2[h * 10 + c] : 0.f;
    b2T[gid] = (__bf16)v;
    a2 = fabsf(v);
  }
  #pragma unroll
  for (int off = 32; off > 0; off >>= 1) {
    s1 += __shfl_down(s1, off);
    s2 += __shfl_down(s2, off);
    a1 += __shfl_down(a1, off);
    a2 += __shfl_down(a2, off);
  }
  if ((threadIdx.x & 63) == 0) {
    atomicAdd(&wsf[1], s1);
    atomicAdd(&wsf[2], s2);
    if (blockIdx.x < 256) atomicAdd(&wsf[3], a1);
    if (blockIdx.x < 16)  atomicAdd(&wsf[4], a2);
  }
}

// ---------------- gram = x^T diag(w^2) x  (+ col = x^T w^2) ----------------
// 256 blocks x 1024 rows; k-chunk 64; transposed staging via coalesced scalar
// loads (lane=column) + packed ds_write_b64 of 4 consecutive k.
extern "C" __global__ __launch_bounds__(512, 2) void gram_k(
    const float* __restrict__ x, float* __restrict__ wsf) {
  const float* weight = wsf + OFF_WT;
  float* gram = wsf + OFF_GRAM + (blockIdx.x & 3) * 65536;
  __shared__ __bf16 xT[256 * 72];    // [col][k64], stride 72 (144B, 16B-aligned)
  __shared__ __bf16 wxT[256 * 72];
  const int tid = threadIdx.x;
  const int wv = tid >> 6, L = tid & 63;
  const int l32 = L & 31, lh = L >> 5;
  const int mb = 64 * (wv >> 1), nb = 128 * (wv & 1);
  const int col = tid & 255, rh = tid >> 8;   // lane=column; rh picks 32-row half
  const int base = blockIdx.x * 1024;
  v16f acc[2][4] = {};
  float colAcc = 0.f;

  for (int ch = 0; ch < 16; ch++) {
    int k0 = base + 64 * ch;
    __syncthreads();
    #pragma unroll
    for (int s = 0; s < 8; s++) {
      int krow = 32 * rh + 4 * s;
      float v0 = x[(k0 + krow + 0) * 256 + col];
      float v1 = x[(k0 + krow + 1) * 256 + col];
      float v2 = x[(k0 + krow + 2) * 256 + col];
      float v3 = x[(k0 + krow + 3) * 256 + col];
      float w0 = weight[k0 + krow + 0];
      float w1 = weight[k0 + krow + 1];
      float w2 = weight[k0 + krow + 2];
      float w3 = weight[k0 + krow + 3];
      colAcc += w0 * v0 + w1 * v1 + w2 * v2 + w3 * v3;
      v4bf xa, wa;
      xa[0] = (__bf16)v0; xa[1] = (__bf16)v1; xa[2] = (__bf16)v2; xa[3] = (__bf16)v3;
      wa[0] = (__bf16)(w0 * v0); wa[1] = (__bf16)(w1 * v1);
      wa[2] = (__bf16)(w2 * v2); wa[3] = (__bf16)(w3 * v3);
      *(v4bf*)&xT[col * 72 + krow]  = xa;
      *(v4bf*)&wxT[col * 72 + krow] = wa;
    }
    __syncthreads();
    #pragma unroll
    for (int ks = 0; ks < 64; ks += 16) {
      v8bf a0 = *(const v8bf*)&xT[(mb + l32) * 72 + ks + 8 * lh];
      v8bf a1 = *(const v8bf*)&xT[(mb + 32 + l32) * 72 + ks + 8 * lh];
      v8bf b[4];
      #pragma unroll
      for (int tn = 0; tn < 4; tn++)
        b[tn] = *(const v8bf*)&wxT[(nb + 32 * tn + l32) * 72 + ks + 8 * lh];
      #pragma unroll
      for (int tn = 0; tn < 4; tn++) {
        acc[0][tn] = __builtin_amdgcn_mfma_f32_32x32x16_bf16(a0, b[tn], acc[0][tn], 0, 0, 0);
        acc[1][tn] = __builtin_amdgcn_mfma_f32_32x32x16_bf16(a1, b[tn], acc[1][tn], 0, 0, 0);
      }
    }
  }
  #pragma unroll
  for (int tm = 0; tm < 2; tm++)
    #pragma unroll
    for (int tn = 0; tn < 4; tn++)
      #pragma unroll
      for (int r = 0; r < 16; r++) {
        int row = mb + 32 * tm + (r & 3) + 8 * (r >> 2) + 4 * lh;
        int cg = nb + 32 * tn + l32;
        atomicAdd(&gram[row * 256 + cg], acc[tm][tn][r]);
      }
  atomicAdd(&wsf[OFF_COL + col], colAcc);
}

// ---------------- mlp: hdn=relu(x@b1), dropout, logits, CE, argmax ----------------
// 4096 blocks x 64 rows; wave-tile 64x64 (acc=64 f32) -> 4 waves/SIMD target.
extern "C" __global__ __launch_bounds__(256, 4) void mlp_k(
    const float* __restrict__ x, const int* __restrict__ y,
    const float* __restrict__ du, float* __restrict__ wsf) {
  const __bf16* b1T = (const __bf16*)((const char*)wsf + B1T_BYTE);
  const __bf16* b2T = (const __bf16*)((const char*)wsf + B2T_BYTE);
  __shared__ union U {
    struct { __bf16 xs[64 * 40]; __bf16 b1s[256 * 40]; } m;   // 5120 + 20480 B
    struct { __bf16 hk[64 * 264]; float lg[64 * 16]; } l;     // 33792 + 4096 B
  } sm;
  const int tid = threadIdx.x;
  const int wv = tid >> 6, L = tid & 63;
  const int l32 = L & 31, lh = L >> 5;
  const int nb = 64 * wv;                    // wave owns 64 h-cols
  const int rowBase = blockIdx.x * 64;

  v16f acc[2][2] = {};

  for (int kc = 0; kc < 256; kc += 32) {
    __syncthreads();
    // stage x chunk [64 rows x 32 k] fp32 -> bf16, stride 40
    #pragma unroll
    for (int i = 0; i < 2; i++) {
      int f = tid + 256 * i;
      int r = f >> 3, c4 = f & 7;
      f4v v = ((const f4v*)x)[(rowBase + r) * 64 + (kc >> 2) + c4];
      v4bf o;
      o[0] = (__bf16)v[0]; o[1] = (__bf16)v[1]; o[2] = (__bf16)v[2]; o[3] = (__bf16)v[3];
      *(v4bf*)&sm.m.xs[r * 40 + 4 * c4] = o;
    }
    // stage b1T chunk [256 n x 32 k] bf16 copy, stride 40
    #pragma unroll
    for (int i = 0; i < 4; i++) {
      int f = tid + 256 * i;
      int nr = f >> 2, c = f & 3;
      *(v8bf*)&sm.m.b1s[nr * 40 + 8 * c] = *(const v8bf*)&b1T[nr * 256 + kc + 8 * c];
    }
    __syncthreads();
    #pragma unroll
    for (int ks = 0; ks < 32; ks += 16) {
      v8bf a0 = *(const v8bf*)&sm.m.xs[(l32) * 40 + ks + 8 * lh];
      v8bf a1 = *(const v8bf*)&sm.m.xs[(32 + l32) * 40 + ks + 8 * lh];
      v8bf b0 = *(const v8bf*)&sm.m.b1s[(nb + l32) * 40 + ks + 8 * lh];
      v8bf b1f = *(const v8bf*)&sm.m.b1s[(nb + 32 + l32) * 40 + ks + 8 * lh];
      acc[0][0] = __builtin_amdgcn_mfma_f32_32x32x16_bf16(a0, b0,  acc[0][0], 0, 0, 0);
      acc[0][1] = __builtin_amdgcn_mfma_f32_32x32x16_bf16(a0, b1f, acc[0][1], 0, 0, 0);
      acc[1][0] = __builtin_amdgcn_mfma_f32_32x32x16_bf16(a1, b0,  acc[1][0], 0, 0, 0);
      acc[1][1] = __builtin_amdgcn_mfma_f32_32x32x16_bf16(a1, b1f, acc[1][1], 0, 0, 0);
    }
  }
  // relu + inverted dropout (C layout: col=lane&31, row=(r&3)+8*(r>>2)+4*lh)
  #pragma unroll
  for (int tm = 0; tm < 2; tm++)
    #pragma unroll
    for (int tn = 0; tn < 2; tn++)
      #pragma unroll
      for (int r = 0; r < 16; r++) {
        int row = 32 * tm + (r & 3) + 8 * (r >> 2) + 4 * lh;
        int cg = nb + 32 * tn + l32;
        float u = du[(rowBase + row) * 256 + cg];
        float v = acc[tm][tn][r];
        v = fmaxf(v, 0.f);
        acc[tm][tn][r] = (u > 0.3f) ? v * (1.0f / 0.7f) : 0.f;
      }

  // spill P to LDS full-width [64][264], all waves at once
  __syncthreads();
  #pragma unroll
  for (int tm = 0; tm < 2; tm++)
    #pragma unroll
    for (int tn = 0; tn < 2; tn++)
      #pragma unroll
      for (int r = 0; r < 16; r++) {
        int row = 32 * tm + (r & 3) + 8 * (r >> 2) + 4 * lh;
        int cg = nb + 32 * tn + l32;
        sm.l.hk[row * 264 + cg] = (__bf16)acc[tm][tn][r];
      }
  __syncthreads();
  // logits: wave wv -> m-tile rows [16wv,16wv+16), K=256 via 8x 16x16x32
  v4f lacc = {};
  #pragma unroll
  for (int kk = 0; kk < 8; kk++) {
    v8bf a  = *(const v8bf*)&sm.l.hk[(16 * wv + (L & 15)) * 264 + 32 * kk + 8 * (L >> 4)];
    v8bf bb = *(const v8bf*)&b2T[(L & 15) * 256 + 32 * kk + 8 * (L >> 4)];
    lacc = __builtin_amdgcn_mfma_f32_16x16x32_bf16(a, bb, lacc, 0, 0, 0);
  }
  #pragma unroll
  for (int r = 0; r < 4; r++)
    sm.l.lg[(16 * wv + 4 * (L >> 4) + r) * 16 + (L & 15)] = lacc[r];
  __syncthreads();
  float ce = 0.f;
  int cor = 0;
  if (tid < 64) {
    const float* lr = &sm.l.lg[tid * 16];
    float mx = lr[0];
    int am = 0;
    #pragma unroll
    for (int c = 1; c < 10; c++)
      if (lr[c] > mx) { mx = lr[c]; am = c; }   // strict > = first-max (jnp semantics)
    float s = 0.f;
    #pragma unroll
    for (int c = 0; c < 10; c++) s += expf(lr[c] - mx);
    int yt = y[rowBase + tid];
    ce = logf(s) + mx - lr[yt];
    cor = (am == yt) ? 1 : 0;
  }
  if (wv == 0) {
    #pragma unroll
    for (int off = 32; off > 0; off >>= 1) ce += __shfl_down(ce, off);
    unsigned long long bal = __ballot(cor != 0);
    if (L == 0) {
      atomicAdd(&wsf[0], ce);
      atomicAdd((int*)&wsf[8], (int)__popcll(bal));
    }
  }
}

// ---------------- finalize: bm, loss, acc ----------------
extern "C" __global__ __launch_bounds__(1024) void fin_k(
    const float* __restrict__ wsf, float* __restrict__ out) {
  __shared__ float colS[256];
  __shared__ float red[1024];
  int tid = threadIdx.x;
  if (tid < 256) colS[tid] = wsf[OFF_COL + tid];
  __syncthreads();
  int t = tid & 255, q = tid >> 8;
  const float* g = wsf + OFF_GRAM;
  float ct = colS[t];
  float bm = 0.f;
  for (int j = 64 * q; j < 64 * q + 64; j++) {
    float gv = g[j * 256 + t] + g[65536 + j * 256 + t]
             + g[131072 + j * 256 + t] + g[196608 + j * 256 + t];
    float d = gv - colS[j] * ct;
    bm += (j != t) ? d * d : 0.f;
  }
  red[tid] = bm;
  __syncthreads();
  for (int s = 512; s > 0; s >>= 1) {
    if (tid < s) red[tid] += red[tid + s];
    __syncthreads();
  }
  if (tid == 0) {
    float ce = wsf[0], wsum = wsf[1], w4 = wsf[2], ab1 = wsf[3], ab2 = wsf[4];
    int cor = *(const int*)&wsf[8];
    float loss = ce * wsum
               + 0.01f * (ab1 + ab2)
               + 0.001f * red[0]
               + 0.1f * w4
               + 100.f * (wsum - 1.f) * (wsum - 1.f);
    out[0] = loss;
    out[1] = (float)cor * (1.0f / 262144.0f);
  }
}

extern "C" void kernel_launch(void* const* d_in, const int* in_sizes, int n_in,
                              void* d_out, int out_size, void* d_ws, size_t ws_size,
                              hipStream_t stream) {
  const float* x  = (const float*)d_in[0];
  const int*   y  = (const int*)d_in[1];
  const float* du = (const float*)d_in[2];
  const float* b1 = (const float*)d_in[3];
  const float* b2 = (const float*)d_in[4];
  const float* w  = (const float*)d_in[5];
  float* wsf = (float*)d_ws;

  hipMemsetAsync(d_ws, 0, ZERO_BYTES, stream);   // zero scalars + col + gram copies
  prep_k<<<1024, 256, 0, stream>>>(w, b1, b2, wsf);
  gram_k<<<256, 512, 0, stream>>>(x, wsf);       // before mlp: leaves x warm in L3
  mlp_k<<<4096, 256, 0, stream>>>(x, y, du, wsf);
  fin_k<<<1, 1024, 0, stream>>>(wsf, (float*)d_out);
}